// Round 10
// baseline (302.757 us; speedup 1.0000x reference)
//
#include <hip/hip_runtime.h>
#include <stdint.h>
#include <math.h>

#define SEQ 4096
#define DM  1024
#define NH  16
#define DH  64
#define PSTR 36
#define LOG2E 1.44269504088896341f

typedef short bf16x8 __attribute__((ext_vector_type(8)));
typedef short bf16x4 __attribute__((ext_vector_type(4)));
typedef float f32x4  __attribute__((ext_vector_type(4)));

typedef const __attribute__((address_space(1))) short* gptr_t;
typedef __attribute__((address_space(3))) short* lptr_t;

__device__ __forceinline__ short f2bf(float f) {
    union { float f; uint32_t u; } x; x.f = f;
    uint32_t r = (x.u + 0x7fffu + ((x.u >> 16) & 1u)) >> 16;
    return (short)r;
}
__device__ __forceinline__ uint32_t fbits(float f) {
    union { float f; uint32_t u; } x; x.f = f; return x.u;
}
__device__ __forceinline__ float bits2f(uint32_t u) {
    union { uint32_t u; float f; } x; x.u = u; return x.f;
}

__device__ __forceinline__ void load_lds16(const short* g, const short* l) {
    __builtin_amdgcn_global_load_lds((gptr_t)(uintptr_t)g,
                                     (lptr_t)(uint32_t)(uintptr_t)l, 16, 0, 0);
}

// ---- fused prep: blocks [0,2048) convert x fp32->bf16; blocks [2048,2816)
//      transpose w [1024][3072] -> wtb [3072][1024] bf16, Q cols pre-scaled ----
__global__ __launch_bounds__(256) void cvt_fused(const float* __restrict__ x,
                                                 const float* __restrict__ w,
                                                 short* __restrict__ xb,
                                                 short* __restrict__ wtb) {
    __shared__ float T[64][69];
    const int b = blockIdx.x;
    if (b < 2048) {
        const int i = (b * 256 + threadIdx.x) * 8;
        float4 a0 = ((const float4*)(x + i))[0];
        float4 a1 = ((const float4*)(x + i))[1];
        bf16x8 p;
        p[0]=f2bf(a0.x); p[1]=f2bf(a0.y); p[2]=f2bf(a0.z); p[3]=f2bf(a0.w);
        p[4]=f2bf(a1.x); p[5]=f2bf(a1.y); p[6]=f2bf(a1.z); p[7]=f2bf(a1.w);
        *(bf16x8*)(xb + i) = p;
        return;
    }
    const int bb = b - 2048;
    const int n0 = (bb % 48) * 64, k0 = (bb / 48) * 64;
    const int t = threadIdx.x;
    {
        const int kr = t >> 4, nc = (t & 15) * 4;
        #pragma unroll
        for (int i = 0; i < 4; ++i) {
            float4 v = *(const float4*)(w + (size_t)(k0 + kr + i * 16) * 3072 + n0 + nc);
            T[kr + i * 16][nc + 0] = v.x; T[kr + i * 16][nc + 1] = v.y;
            T[kr + i * 16][nc + 2] = v.z; T[kr + i * 16][nc + 3] = v.w;
        }
    }
    __syncthreads();
    const int nr = t >> 4, kc = (t & 15) * 4;
    #pragma unroll
    for (int i = 0; i < 4; ++i) {
        const int n = n0 + nr + i * 16;
        const float sc = (n >= 1024 && n < 2048) ? (LOG2E / 32.0f) : 1.0f;
        short4 o;
        o.x = f2bf(T[kc + 0][nr + i * 16] * sc);
        o.y = f2bf(T[kc + 1][nr + i * 16] * sc);
        o.z = f2bf(T[kc + 2][nr + i * 16] * sc);
        o.w = f2bf(T[kc + 3][nr + i * 16] * sc);
        *(short4*)(wtb + (size_t)n * 1024 + k0 + kc) = o;
    }
}

// ---- QKV GEMM (m97 structure): 128x128 tile, BK=64, global_load_lds ----
__global__ __launch_bounds__(256) void qkv_gemm(const short* __restrict__ xb,
                                                const short* __restrict__ wtb,
                                                short* __restrict__ kq,
                                                short* __restrict__ vt) {
    __shared__ short As[128 * 64];
    __shared__ short Bs[128 * 64];
    const int col0 = blockIdx.y * 128, row0 = blockIdx.x * 128;
    const int tid = threadIdx.x, w = tid >> 6, lane = tid & 63;
    const int lmod = lane & 15, ldiv = lane >> 4;
    const int wr = (w >> 1) * 64, wc = (w & 1) * 64;

    f32x4 acc[4][4] = {};
    const short* Ag = xb  + (size_t)row0 * DM;
    const short* Bg = wtb + (size_t)col0 * DM;

    for (int k0 = 0; k0 < DM; k0 += 64) {
        __syncthreads();
        #pragma unroll
        for (int t = 0; t < 4; ++t) {
            const int o = (w * 4 + t) * 1024 + lane * 16;
            const int r = o >> 7, cs = (o & 127) >> 1;
            load_lds16(Ag + (size_t)r * DM + k0 + cs, As + (w * 4 + t) * 512);
            load_lds16(Bg + (size_t)r * DM + k0 + cs, Bs + (w * 4 + t) * 512);
        }
        __syncthreads();
        #pragma unroll
        for (int ks = 0; ks < 2; ++ks) {
            bf16x8 af[4], bf[4];
            #pragma unroll
            for (int i = 0; i < 4; ++i)
                af[i] = *(const bf16x8*)(As + (wr + i * 16 + lmod) * 64 + ks * 32 + ldiv * 8);
            #pragma unroll
            for (int j = 0; j < 4; ++j)
                bf[j] = *(const bf16x8*)(Bs + (wc + j * 16 + lmod) * 64 + ks * 32 + ldiv * 8);
            #pragma unroll
            for (int i = 0; i < 4; ++i)
                #pragma unroll
                for (int j = 0; j < 4; ++j)
                    acc[i][j] = __builtin_amdgcn_mfma_f32_16x16x32_bf16(af[i], bf[j], acc[i][j], 0, 0, 0);
        }
    }

    if (col0 < 2048) {
        #pragma unroll
        for (int i = 0; i < 4; ++i)
            #pragma unroll
            for (int j = 0; j < 4; ++j)
                #pragma unroll
                for (int r = 0; r < 4; ++r)
                    kq[(size_t)(row0 + wr + i * 16 + ldiv * 4 + r) * 2048
                       + col0 + wc + j * 16 + lmod] = f2bf(acc[i][j][r]);
    } else {
        #pragma unroll
        for (int i = 0; i < 4; ++i) {
            const int ig = row0 + wr + i * 16 + ldiv * 4;
            #pragma unroll
            for (int j = 0; j < 4; ++j) {
                const int cg = col0 + wc + j * 16 + lmod - 2048;
                const int h = cg >> 6, d = cg & 63;
                bf16x4 p;
                p[0]=f2bf(acc[i][j][0]); p[1]=f2bf(acc[i][j][1]);
                p[2]=f2bf(acc[i][j][2]); p[3]=f2bf(acc[i][j][3]);
                *(bf16x4*)(vt + (size_t)(h * 64 + d) * SEQ + ig) = p;
            }
        }
    }
}

// ---- flash attention, split-K 4-way, S^T orientation, half-tile P.
//      Block (qt desc, h, s): k-tiles [sT/4, (s+1)T/4). Partial O stored as
//      bf16 planes via 16-bit stores: s=0/1 -> lo/hi shorts of d_out dwords,
//      s=2/3 -> lo/hi shorts of p23. No atomics. Empty chunks zero-fill.
//      LDS 25.0 KB -> up to 6 blocks/CU. ----
__global__ __launch_bounds__(256, 5) void attn(const short* __restrict__ kq,
                                               const short* __restrict__ vt,
                                               short* __restrict__ outp,
                                               short* __restrict__ p23,
                                               float* __restrict__ ls) {
    __shared__ short Ks[64 * 64];
    __shared__ short Vs[64 * 64];
    __shared__ short Ps[4 * 32 * PSTR];

    const int b = blockIdx.x;
    const int qt = 31 - (b >> 6);            // LPT: heavy first
    const int h = (b >> 2) & 15, s = b & 3;
    const int T = 2 * qt + 2;
    const int c0 = (s * T) >> 2, c1 = ((s + 1) * T) >> 2;

    const int tid = threadIdx.x, w = tid >> 6, lane = tid & 63;
    const int lmod = lane & 15, ldiv = lane >> 4;
    const int rowbase = qt * 128 + w * 32;
    short* po = ((s < 2) ? outp : p23) + (s & 1);

    if (c0 == c1) {   // empty chunk: zero our plane + lsum (poison safety)
        #pragma unroll
        for (int ib = 0; ib < 2; ++ib) {
            const int i0 = rowbase + ib * 16 + ldiv * 4;
            #pragma unroll
            for (int nt = 0; nt < 4; ++nt)
                #pragma unroll
                for (int r = 0; r < 4; ++r)
                    po[2 * ((size_t)(i0 + r) * DM + h * 64 + nt * 16 + lmod)] = 0;
        }
        if (ldiv == 0) {
            #pragma unroll
            for (int ib = 0; ib < 2; ++ib)
                ls[s * (NH * SEQ) + h * SEQ + rowbase + ib * 16 + lmod] = 0.f;
        }
        return;
    }

    const float slope2 = exp2f(-0.5f * (float)(h + 1)) * LOG2E;

    // staging (wave w -> rows w*16..+15), XOR swizzle on global source chunk
    const int sr0 = w * 16 + (lane >> 3), sr1 = sr0 + 8;
    const int sc0 = (lane & 7) ^ (sr0 & 7), sc1 = (lane & 7) ^ (sr1 & 7);
    const int xorm = lmod & 7;
    short* pw = Ps + w * 32 * PSTR;

    // Q fragments (B-operand; n=i=lmod, k=d)
    bf16x8 qf[2][2];
    #pragma unroll
    for (int ib = 0; ib < 2; ++ib) {
        const short* qp = kq + (size_t)(rowbase + ib * 16 + lmod) * 2048 + 1024 + h * 64;
        qf[ib][0] = *(const bf16x8*)(qp + ldiv * 8);
        qf[ib][1] = *(const bf16x8*)(qp + 32 + ldiv * 8);
    }
    // j - i = kt*64 + hh*32 + jb*16 + ldiv*4 + r - (rowbase + ib*16 + lmod)
    int dbI[2];
    float pre[2][4];
    #pragma unroll
    for (int ib = 0; ib < 2; ++ib) {
        dbI[ib] = ldiv * 4 - rowbase - ib * 16 - lmod;
        #pragma unroll
        for (int r = 0; r < 4; ++r) pre[ib][r] = slope2 * (float)(dbI[ib] + r);
    }

    f32x4 O[2][4] = {};
    float lsum[2] = {0.f, 0.f};

    for (int kt = c0; kt < c1; ++kt) {
        __syncthreads();
        {
            const short* kb = kq + (size_t)(kt * 64) * 2048 + h * 64;
            load_lds16(kb + (size_t)sr0 * 2048 + sc0 * 8, Ks + (w * 16) * 64);
            load_lds16(kb + (size_t)sr1 * 2048 + sc1 * 8, Ks + (w * 16 + 8) * 64);
            const short* vb = vt + (size_t)(h * 64) * SEQ + kt * 64;
            load_lds16(vb + (size_t)sr0 * SEQ + sc0 * 8, Vs + (w * 16) * 64);
            load_lds16(vb + (size_t)sr1 * SEQ + sc1 * 8, Vs + (w * 16 + 8) * 64);
        }
        __syncthreads();

        const bool diag = (kt >= 2 * qt);
        const int dt = kt * 64;

        #pragma unroll
        for (int hh = 0; hh < 2; ++hh) {          // j-half 0..31 / 32..63
            #pragma unroll
            for (int jb = 0; jb < 2; ++jb) {      // 16-j block within half
                const int jcb = dt + hh * 32 + jb * 16;
                const float cn = slope2 * (float)jcb;
                f32x4 sc[2];
                #pragma unroll
                for (int ib = 0; ib < 2; ++ib)
                    #pragma unroll
                    for (int r = 0; r < 4; ++r) sc[ib][r] = pre[ib][r] + cn;
                #pragma unroll
                for (int ks = 0; ks < 2; ++ks) {
                    const int cxo = (((ks << 2) + ldiv) ^ xorm) << 3;
                    bf16x8 kf = *(const bf16x8*)(Ks + (hh * 32 + jb * 16 + lmod) * 64 + cxo);
                    #pragma unroll
                    for (int ib = 0; ib < 2; ++ib)
                        sc[ib] = __builtin_amdgcn_mfma_f32_16x16x32_bf16(kf, qf[ib][ks], sc[ib], 0, 0, 0);
                }
                #pragma unroll
                for (int ib = 0; ib < 2; ++ib) {
                    float p0, p1, p2, p3;
                    if (diag) {
                        const int dj = jcb + dbI[ib];
                        p0 = __builtin_amdgcn_exp2f((dj + 0 > 0) ? -1e30f : sc[ib][0]);
                        p1 = __builtin_amdgcn_exp2f((dj + 1 > 0) ? -1e30f : sc[ib][1]);
                        p2 = __builtin_amdgcn_exp2f((dj + 2 > 0) ? -1e30f : sc[ib][2]);
                        p3 = __builtin_amdgcn_exp2f((dj + 3 > 0) ? -1e30f : sc[ib][3]);
                    } else {
                        p0 = __builtin_amdgcn_exp2f(sc[ib][0]);
                        p1 = __builtin_amdgcn_exp2f(sc[ib][1]);
                        p2 = __builtin_amdgcn_exp2f(sc[ib][2]);
                        p3 = __builtin_amdgcn_exp2f(sc[ib][3]);
                    }
                    lsum[ib] += (p0 + p1) + (p2 + p3);
                    uint2 pk;
                    pk.x = (fbits(p0) >> 16) | (fbits(p1) & 0xFFFF0000u);
                    pk.y = (fbits(p2) >> 16) | (fbits(p3) & 0xFFFF0000u);
                    *(uint2*)(pw + (ib * 16 + lmod) * PSTR + jb * 16 + ldiv * 4) = pk;
                }
            }
            // read P A-frags for this half (same-wave LDS ordering: no barrier)
            bf16x8 pa[2];
            #pragma unroll
            for (int ib = 0; ib < 2; ++ib)
                pa[ib] = *(const bf16x8*)(pw + (ib * 16 + lmod) * PSTR + ldiv * 8);
            const int cxo = (((hh << 2) + ldiv) ^ xorm) << 3;
            #pragma unroll
            for (int nt = 0; nt < 4; ++nt) {
                bf16x8 vf = *(const bf16x8*)(Vs + (nt * 16 + lmod) * 64 + cxo);
                #pragma unroll
                for (int ib = 0; ib < 2; ++ib)
                    O[ib][nt] = __builtin_amdgcn_mfma_f32_16x16x32_bf16(pa[ib], vf, O[ib][nt], 0, 0, 0);
            }
        }
    }

    // lsum: reduce across quads (lanes sharing lmod)
    #pragma unroll
    for (int ib = 0; ib < 2; ++ib) {
        float v = lsum[ib];
        v += __shfl_xor(v, 16);
        v += __shfl_xor(v, 32);
        lsum[ib] = v;
    }
    if (ldiv == 0) {
        #pragma unroll
        for (int ib = 0; ib < 2; ++ib)
            ls[s * (NH * SEQ) + h * SEQ + rowbase + ib * 16 + lmod] = lsum[ib];
    }
    #pragma unroll
    for (int ib = 0; ib < 2; ++ib) {
        const int i0 = rowbase + ib * 16 + ldiv * 4;
        #pragma unroll
        for (int nt = 0; nt < 4; ++nt)
            #pragma unroll
            for (int r = 0; r < 4; ++r)
                po[2 * ((size_t)(i0 + r) * DM + h * 64 + nt * 16 + lmod)] =
                    f2bf(O[ib][nt][r]);
    }
}

// ---- combine: out = (sum of 4 bf16 planes) / (sum of 4 lsums) ----
__global__ __launch_bounds__(256) void combine(float* __restrict__ out,
                                               const short* __restrict__ p23,
                                               const float* __restrict__ ls) {
    const int i8 = (blockIdx.x * 256 + threadIdx.x) * 8;
    const int row = i8 >> 10, h = (i8 & 1023) >> 6;
    const int li = h * SEQ + row;
    const float rc = 1.0f / (ls[li] + ls[NH * SEQ + li] +
                             ls[2 * NH * SEQ + li] + ls[3 * NH * SEQ + li]);
    const uint32_t* ob = (const uint32_t*)out;
    const uint32_t* pb = (const uint32_t*)p23;
    float4 r0, r1;
    uint4 a = *(const uint4*)(ob + i8);
    uint4 c = *(const uint4*)(pb + i8);
    r0.x = (bits2f(a.x << 16) + bits2f(a.x & 0xFFFF0000u) + bits2f(c.x << 16) + bits2f(c.x & 0xFFFF0000u)) * rc;
    r0.y = (bits2f(a.y << 16) + bits2f(a.y & 0xFFFF0000u) + bits2f(c.y << 16) + bits2f(c.y & 0xFFFF0000u)) * rc;
    r0.z = (bits2f(a.z << 16) + bits2f(a.z & 0xFFFF0000u) + bits2f(c.z << 16) + bits2f(c.z & 0xFFFF0000u)) * rc;
    r0.w = (bits2f(a.w << 16) + bits2f(a.w & 0xFFFF0000u) + bits2f(c.w << 16) + bits2f(c.w & 0xFFFF0000u)) * rc;
    a = *(const uint4*)(ob + i8 + 4);
    c = *(const uint4*)(pb + i8 + 4);
    r1.x = (bits2f(a.x << 16) + bits2f(a.x & 0xFFFF0000u) + bits2f(c.x << 16) + bits2f(c.x & 0xFFFF0000u)) * rc;
    r1.y = (bits2f(a.y << 16) + bits2f(a.y & 0xFFFF0000u) + bits2f(c.y << 16) + bits2f(c.y & 0xFFFF0000u)) * rc;
    r1.z = (bits2f(a.z << 16) + bits2f(a.z & 0xFFFF0000u) + bits2f(c.z << 16) + bits2f(c.z & 0xFFFF0000u)) * rc;
    r1.w = (bits2f(a.w << 16) + bits2f(a.w & 0xFFFF0000u) + bits2f(c.w << 16) + bits2f(c.w & 0xFFFF0000u)) * rc;
    *(float4*)(out + i8) = r0;
    *(float4*)(out + i8 + 4) = r1;
}

extern "C" void kernel_launch(void* const* d_in, const int* in_sizes, int n_in,
                              void* d_out, int out_size, void* d_ws, size_t ws_size,
                              hipStream_t stream) {
    const float* x = (const float*)d_in[0];   // [1,4096,1024] fp32
    const float* w = (const float*)d_in[1];   // [1024,3072] fp32
    float* out = (float*)d_out;

    char* ws = (char*)d_ws;
    short* kq  = (short*)(ws);                        // 16 MB: K|Q [4096][2048]
    short* vt  = (short*)(ws + ((size_t)16 << 20));   //  8 MB: V^T [16][64][4096]
    short* xb  = (short*)(ws + ((size_t)24 << 20));   //  8 MB: x bf16 (dead after gemm)
    short* wtb = (short*)(ws + ((size_t)32 << 20));   //  6 MB: w^T bf16 (dead after gemm)
    short* p23 = (short*)(ws + ((size_t)24 << 20));   // 16 MB: planes 2/3 (alias xb+wtb)
    float* ls  = (float*)(ws + ((size_t)40 << 20));   //  1 MB: lsum [4][16][4096]

    cvt_fused<<<2048 + 768, 256, 0, stream>>>(x, w, xb, wtb);
    qkv_gemm <<<dim3(SEQ / 128, 3072 / 128), 256, 0, stream>>>(xb, wtb, kq, vt);
    attn     <<<2048, 256, 0, stream>>>(kq, vt, (short*)out, p23, ls);
    combine  <<<SEQ * DM / (256 * 8), 256, 0, stream>>>(out, p23, ls);
}